// Round 10
// baseline (269.024 us; speedup 1.0000x reference)
//
#include <hip/hip_runtime.h>

#define NV    10
#define DD    2048
#define TAPS  25
#define CHUNK 128               // channels per staged chunk
#define NCH   (DD / CHUNK)      // 16 chunks
#define OB    64

__device__ __forceinline__ float bsign(float v) {
    return (v > 0.0f) ? 1.0f : ((v < 0.0f) ? -1.0f : 0.0f);
}

// ===================== R10 = ATTRIBUTION ROUND =====================
// g_kernel and out_kernel are byte-identical to R9. kernel_launch runs
// g_kernel TWICE (idempotent: same G written both times, stream-ordered,
// deterministic) so dur(R10) - dur(R9) = g_kernel's wall time.
// ===================================================================

__global__ __launch_bounds__(256) void g_kernel(
        const float* __restrict__ values,
        const float* __restrict__ w,
        float* __restrict__ G) {
    const int o    = blockIdx.x;
    const int t    = threadIdx.x;
    const int lane = t & 63;
    const int wv   = t >> 6;

    __shared__ float4 buf4[CHUNK * TAPS / 4];       // 800 float4 = 12.8 KB, single buffer
    __shared__ unsigned long long s_vnz[32 * NV];   // [g][n]
    __shared__ unsigned long long s_vng[32 * NV];

    const float4* wf4 = (const float4*)(w + (size_t)o * (DD * TAPS));  // 800 f4 per chunk

    // value sign/nonzero masks (values = 80 KB, L2/L3-hot); issued before reg-loads
    for (int t2 = wv; t2 < 32 * NV; t2 += 4) {      // t2 wave-uniform
        const int g = t2 / NV;
        const int n = t2 - g * NV;
        float f = values[n * DD + g * 64 + lane];
        unsigned long long nz = __ballot(f != 0.0f);
        unsigned long long ng = __ballot(f < 0.0f);
        if (lane == 0) { s_vnz[g * NV + n] = nz; s_vng[g * NV + n] = ng; }
    }

    float4 r0, r1, r2, r3;
    #define LOADREGS(ch) do {                                   \
        const float4* p_ = wf4 + (size_t)(ch) * 800;            \
        r0 = p_[t]; r1 = p_[t + 256]; r2 = p_[t + 512];         \
        if (t < 32) r3 = p_[t + 768];                           \
    } while (0)
    #define WRITEREGS() do {                                    \
        buf4[t] = r0; buf4[t + 256] = r1; buf4[t + 512] = r2;   \
        if (t < 32) buf4[t + 768] = r3;                         \
    } while (0)

    LOADREGS(0);
    WRITEREGS();                                     // waits vmcnt via r* data deps only
    LOADREGS(1);                                     // chunk 1 into flight
    asm volatile("s_waitcnt lgkmcnt(0)" ::: "memory");
    __builtin_amdgcn_s_barrier();                    // buf = chunk 0; masks visible

    int acc[7] = {0, 0, 0, 0, 0, 0, 0};             // lanes 0..9: (tap = 4k+wv, n = lane)
    const float* buf = (const float*)buf4;

    for (int ch = 0; ch < NCH; ++ch) {
        unsigned long long vz0 = 0, vg0 = 0, vz1 = 0, vg1 = 0;
        if (lane < NV) {
            const int g0 = ch * 2;
            vz0 = s_vnz[g0 * NV + lane];       vg0 = s_vng[g0 * NV + lane];
            vz1 = s_vnz[(g0 + 1) * NV + lane]; vg1 = s_vng[(g0 + 1) * NV + lane];
        }
        #pragma unroll
        for (int k = 0; k < 7; ++k) {
            const int tap = 4 * k + wv;              // wave wv owns taps {wv, wv+4, ...}
            if (tap < TAPS) {
                // lane = channel-in-group; stride-25 words -> 2 lanes/bank, conflict-free
                float f0 = buf[lane * TAPS + tap];           // channels 0..63
                float f1 = buf[(64 + lane) * TAPS + tap];    // channels 64..127
                unsigned long long wng0 = __ballot(f0 <  0.0f);
                unsigned long long wnz0 = __ballot(f0 != 0.0f);
                unsigned long long wng1 = __ballot(f1 <  0.0f);
                unsigned long long wnz1 = __ballot(f1 != 0.0f);
                // exact: S += popc(bothnz) - 2*popc(signdiff & bothnz); zeros handled
                unsigned long long nzb0 = wnz0 & vz0;
                unsigned long long nzb1 = wnz1 & vz1;
                acc[k] += (int)__popcll(nzb0) - 2 * (int)__popcll((wng0 ^ vg0) & nzb0)
                        + (int)__popcll(nzb1) - 2 * (int)__popcll((wng1 ^ vg1) & nzb1);
            }
        }
        __builtin_amdgcn_s_barrier();                // all waves done reading buf
        if (ch + 1 < NCH) {
            WRITEREGS();                             // regs hold ch+1 (landed during compute)
            if (ch + 2 < NCH) LOADREGS(ch + 2);      // next loads into flight immediately
            asm volatile("s_waitcnt lgkmcnt(0)" ::: "memory");
            __builtin_amdgcn_s_barrier();            // buf = ch+1 ready; vmcnt still in flight
        }
    }
    #undef LOADREGS
    #undef WRITEREGS

    // unique (tap,n) ownership -> plain stores, no reduction needed
    if (lane < NV) {
        #pragma unroll
        for (int k = 0; k < 7; ++k) {
            const int tap = 4 * k + wv;
            if (tap < TAPS) {
                G[((size_t)(tap * NV + lane) << 11) + o] = (float)acc[k];
            }
        }
    }
}

// out[b,o,oh,ow] = sign(sum_tap G[idx(tap)][o][tap] + bias[o])  -- unchanged from R9.
// tap-sum is an exact integer in f32; bias added ONCE at the end (bit-exact sign).
__global__ __launch_bounds__(256) void out_kernel(
        const float* __restrict__ x,
        const float* __restrict__ G,
        const float* __restrict__ bias,
        float* __restrict__ out) {
    const int b     = blockIdx.x >> 5;
    const int oc    = blockIdx.x & 31;
    const int obase = oc * OB;
    const int t     = threadIdx.x;

    __shared__ int   s_idx[28 * 28];
    __shared__ float s_out[OB * 145];    // [o_l][pos], odd word-stride: conflict-free

    for (int e = t; e < 28 * 28; e += 256) {
        s_idx[e] = (int)(x[b * 784 + e] * 9.0f);   // trunc, matches .astype(int32)
    }
    __syncthreads();

    const int o_l = t & (OB - 1);
    const int pg  = t >> 6;
    const float bv = bias[obase + o_l];
    const float* Gb = G + obase + o_l;

    for (int p0 = 0; p0 < 144; p0 += 4) {
        const int pos = p0 + pg;
        const int oh  = pos / 12;
        const int ow  = pos - oh * 12;
        float acc = 0.0f;                              // integer-exact accumulation
        #pragma unroll
        for (int kh = 0; kh < 5; ++kh) {
            const int row = (oh * 2 + kh) * 28 + ow * 2;
            #pragma unroll
            for (int kw = 0; kw < 5; ++kw) {
                const int nn = s_idx[row + kw];            // wave-uniform broadcast
                const int tp = kh * 5 + kw;
                acc += Gb[(size_t)(tp * NV + nn) << 11];   // coalesced 256B/wave, L2-hit
            }
        }
        s_out[o_l * 145 + pos] = bsign(acc + bv);
    }
    __syncthreads();

    // block's output region is one contiguous span of OB*144 floats
    float* dst = out + ((size_t)(b * DD + obase)) * 144;
    for (int e = t; e < OB * 144; e += 256) {
        const int ol = e / 144;
        dst[e] = s_out[ol * 145 + (e - ol * 144)];
    }
}

extern "C" void kernel_launch(void* const* d_in, const int* in_sizes, int n_in,
                              void* d_out, int out_size, void* d_ws, size_t ws_size,
                              hipStream_t stream) {
    const float* x      = (const float*)d_in[0];   // [16,1,28,28]
    const float* values = (const float*)d_in[1];   // [10,2048]
    const float* w      = (const float*)d_in[2];   // [2048,2048,5,5] OIHW
    const float* bias   = (const float*)d_in[3];   // [2048]
    float* out = (float*)d_out;                    // [16,2048,12,12]
    float* G   = (float*)d_ws;                     // 25*10*2048 floats = 2 MB scratch

    // ATTRIBUTION: g_kernel launched twice (idempotent, deterministic).
    // dur(R10) - dur(R9) isolates g_kernel's wall time.
    hipLaunchKernelGGL(g_kernel, dim3(DD), dim3(256), 0, stream, values, w, G);
    hipLaunchKernelGGL(g_kernel, dim3(DD), dim3(256), 0, stream, values, w, G);
    hipLaunchKernelGGL(out_kernel, dim3(16 * (DD / OB)), dim3(256), 0, stream, x, G, bias, out);
}

// Round 11
// 123.806 us; speedup vs baseline: 2.1729x; 2.1729x over previous
//
#include <hip/hip_runtime.h>

#define NV    10
#define DD    2048
#define TAPS  25
#define CHUNK 128             // channels per staging chunk
#define NCH   (DD / CHUNK)    // 16 chunks
#define NGRP  (DD / 64)       // 32 groups of 64 channels
#define OB    64

typedef __attribute__((address_space(1))) const unsigned int gu32;
typedef __attribute__((address_space(3))) unsigned int lu32;

__device__ __forceinline__ float bsign(float v) {
    return (v > 0.0f) ? 1.0f : ((v < 0.0f) ? -1.0f : 0.0f);
}

// ---- vpack + g_kernel: VERBATIM from R3 (the measured-best 137.3 config) ----

// Pack sign/nonzero bitmasks of values: one block per (n, 64-ch group).
__global__ __launch_bounds__(64) void vpack_kernel(
        const float* __restrict__ values,
        unsigned long long* __restrict__ vnz,
        unsigned long long* __restrict__ vng) {
    const int b    = blockIdx.x;      // 0..319
    const int n    = b >> 5;
    const int g    = b & 31;
    const int lane = threadIdx.x;
    float f = values[n * DD + g * 64 + lane];
    unsigned long long nz = __ballot(f != 0.0f);
    unsigned long long ng = __ballot(f < 0.0f);
    if (lane == 0) {
        vnz[n * NGRP + g] = nz;
        vng[n * NGRP + g] = ng;
    }
}

// G[tap][n][o] = sum_c sign(values[n][c])*sign(w[o][c][tap]), via ballot+popcount.
__global__ __launch_bounds__(256) void g_kernel(
        const float* __restrict__ w,
        const unsigned long long* __restrict__ gvnz,
        const unsigned long long* __restrict__ gvng,
        float* __restrict__ G) {
    const int o    = blockIdx.x;
    const int t    = threadIdx.x;
    const int lane = t & 63;
    const int wv   = t >> 6;

    __shared__ float ls_raw[CHUNK * TAPS + 32];      // 3200 floats, linear
    __shared__ unsigned long long s_wnz[TAPS * 2];
    __shared__ unsigned long long s_wng[TAPS * 2];
    __shared__ unsigned long long s_vnz[NV * NGRP];
    __shared__ unsigned long long s_vng[NV * NGRP];

    for (int e = t; e < NV * NGRP; e += 256) {
        s_vnz[e] = gvnz[e];
        s_vng[e] = gvng[e];
    }

    const int tap = t / NV;          // accum ownership: t<250 -> (tap, n)
    const int n   = t - tap * NV;
    int acc = 0;

    const float* wo = w + (size_t)o * (DD * TAPS);

    for (int ch = 0; ch < NCH; ++ch) {
        __syncthreads();  // prev pack done reading ls_raw; prev accum done reading masks
        // stage 3200 floats = 800 float4 direct to LDS (linear, wave-uniform base + lane*16)
        const float* src = wo + (size_t)(ch * CHUNK) * TAPS;
        for (int e = t; e < (CHUNK * TAPS) / 4; e += 256) {
            const float* gp = src + 4 * e;
            float* lp = ls_raw + 4 * (e - lane);     // uniform within wave
            __builtin_amdgcn_global_load_lds((gu32*)gp, (lu32*)lp, 16, 0, 0);
        }
        __syncthreads();  // drains vmcnt -> ls_raw valid
        // pack: 50 tasks = (tap, 64c-subgroup); stride-25-word LDS reads (2/bank, free)
        for (int task = wv; task < TAPS * 2; task += 4) {
            const int ptap = task >> 1;
            const int sub  = task & 1;
            float f = ls_raw[(sub * 64 + lane) * TAPS + ptap];
            unsigned long long nz = __ballot(f != 0.0f);
            unsigned long long ng = __ballot(f < 0.0f);
            if (lane == 0) { s_wnz[task] = nz; s_wng[task] = ng; }
        }
        __syncthreads();
        // accumulate: S += popc(bothnz) - 2*popc(signdiff & bothnz)  (exact, incl. zeros)
        if (t < NV * TAPS) {
            #pragma unroll
            for (int sub = 0; sub < 2; ++sub) {
                unsigned long long wnz = s_wnz[tap * 2 + sub];
                unsigned long long wng = s_wng[tap * 2 + sub];
                unsigned long long vz  = s_vnz[n * NGRP + ch * 2 + sub];
                unsigned long long vg  = s_vng[n * NGRP + ch * 2 + sub];
                unsigned long long nzb = wnz & vz;
                unsigned long long df  = (wng ^ vg) & nzb;
                acc += __popcll(nzb) - 2 * __popcll(df);
            }
        }
    }
    if (t < NV * TAPS) {
        G[((size_t)(tap * NV + n) << 11) + o] = (float)acc;
    }
}

// ---- out_kernel: REWRITTEN. G-strip staged in LDS (64 KB, +1-padded rows);
// lanes = positions (coalesced stores); per-position tap row-offsets hoisted to
// 25 registers, reused across 16 o's. Replaces 472 MB of L2 gather traffic with
// conflict-free LDS reads (nn-gather: 10 distinct banks + same-nn broadcast). ----
__global__ __launch_bounds__(256) void out_kernel(
        const float* __restrict__ x,
        const float* __restrict__ G,
        const float* __restrict__ bias,
        float* __restrict__ out) {
    const int b     = blockIdx.x >> 5;     // 16 batches
    const int oc    = blockIdx.x & 31;     // 32 o-strips
    const int obase = oc * OB;
    const int t     = threadIdx.x;
    const int lane  = t & 63;
    const int oq    = t >> 6;              // 0..3: o residue class per wave

    __shared__ float s_G[TAPS * NV * 65];  // [tap*10+n][65]: +1 pad -> nn spreads banks
    __shared__ int   s_idx[28 * 28];
    __shared__ float s_bias[OB];

    // stage G strip: 250 rows x 64 floats (16 float4 each)
    for (int e = t; e < TAPS * NV * 16; e += 256) {
        const int r  = e >> 4;
        const int li = (e & 15) << 2;
        const float4 v = *(const float4*)(G + ((size_t)r << 11) + obase + li);
        s_G[r * 65 + li]     = v.x;
        s_G[r * 65 + li + 1] = v.y;
        s_G[r * 65 + li + 2] = v.z;
        s_G[r * 65 + li + 3] = v.w;
    }
    for (int e = t; e < 28 * 28; e += 256) {
        s_idx[e] = (int)(x[b * 784 + e] * 9.0f);   // trunc, matches .astype(int32)
    }
    if (t < OB) s_bias[t] = bias[obase + t];
    __syncthreads();

    for (int grp = 0; grp < 3; ++grp) {
        const int pos = grp * 64 + lane;
        if (pos < 144) {
            const int oh = pos / 12;
            const int ow = pos - oh * 12;
            int rr[25];                              // static-indexed (fully unrolled)
            #pragma unroll
            for (int kh = 0; kh < 5; ++kh) {
                const int row = (oh * 2 + kh) * 28 + ow * 2;
                #pragma unroll
                for (int kw = 0; kw < 5; ++kw) {
                    const int nn = s_idx[row + kw];          // per-lane index
                    rr[kh * 5 + kw] = (kh * 5 + kw) * 650 + nn * 65;
                }
            }
            for (int ol = oq; ol < OB; ol += 4) {    // 16 o's reuse the 25 offsets
                float acc = 0.0f;                    // integer-exact accumulation
                #pragma unroll
                for (int tp = 0; tp < TAPS; ++tp) {
                    acc += s_G[rr[tp] + ol];         // 10 banks + broadcast: conflict-free
                }
                // bias added once after exact int sum -> bit-exact sign
                out[((size_t)(b * DD + obase + ol)) * 144 + pos] = bsign(acc + s_bias[ol]);
            }
        }
    }
}

extern "C" void kernel_launch(void* const* d_in, const int* in_sizes, int n_in,
                              void* d_out, int out_size, void* d_ws, size_t ws_size,
                              hipStream_t stream) {
    const float* x      = (const float*)d_in[0];   // [16,1,28,28]
    const float* values = (const float*)d_in[1];   // [10,2048]
    const float* w      = (const float*)d_in[2];   // [2048,2048,5,5] OIHW
    const float* bias   = (const float*)d_in[3];   // [2048]
    float* out = (float*)d_out;                    // [16,2048,12,12]

    unsigned long long* vnz = (unsigned long long*)d_ws;          // 2560 B
    unsigned long long* vng = vnz + NV * NGRP;                    // 2560 B
    float* G = (float*)((char*)d_ws + 8192);                      // 2 MB

    hipLaunchKernelGGL(vpack_kernel, dim3(NV * NGRP), dim3(64), 0, stream, values, vnz, vng);
    hipLaunchKernelGGL(g_kernel, dim3(DD), dim3(256), 0, stream, w, vnz, vng, G);
    hipLaunchKernelGGL(out_kernel, dim3(16 * (DD / OB)), dim3(256), 0, stream, x, G, bias, out);
}